// Round 1
// baseline (950.612 us; speedup 1.0000x reference)
//
#include <hip/hip_runtime.h>

#define T_SEQ 4096
#define NBATCH 4
#define EMB 1024
#define HS 64
#define BT (NBATCH * T_SEQ)   // 16384 token rows

__device__ __forceinline__ float dot4f(float4 a, float4 b) {
  return a.x * b.x + a.y * b.y + a.z * b.z + a.w * b.w;
}

// ---------------- Kernel 1: QKV projection ----------------
// C[64tok x 64col] tiles of input @ W{q,k,v}. grid (BT/64, 3), block 256.
// Thread (ib = t>>4, jb = t&15) owns rows {ib+16*ii} x cols {jb+16*jj}
// (strided blocking -> 2-way-max LDS bank aliasing, free on CDNA4).
__global__ __launch_bounds__(256) void qkv_proj(
    const float* __restrict__ inp, const float* __restrict__ Wq,
    const float* __restrict__ Wk, const float* __restrict__ Wv,
    float* __restrict__ ws) {
  __shared__ float As[64 * 68];   // A tile: [tok][emb], stride 68 floats
  __shared__ float Bs[64 * 68];   // W^T tile: [col j][emb e]
  const int t = threadIdx.x;
  const int tile = blockIdx.x;
  const int which = blockIdx.y;
  const float* W = (which == 0) ? Wq : (which == 1) ? Wk : Wv;
  float* outp = ws + (size_t)which * (size_t)BT * HS;
  const int tok0 = tile * 64;
  const int ib = t >> 4, jb = t & 15;
  float acc[4][4] = {};

  for (int e0 = 0; e0 < EMB; e0 += 64) {
    __syncthreads();  // protect LDS from previous chunk's readers
    // A tile: coalesced float4 loads, float4 LDS stores
#pragma unroll
    for (int i = 0; i < 4; ++i) {
      int f = i * 256 + t;           // float4 index 0..1023
      int r = f >> 4, c4 = f & 15;
      float4 v = *(const float4*)&inp[(size_t)(tok0 + r) * EMB + e0 + c4 * 4];
      *(float4*)&As[r * 68 + c4 * 4] = v;
    }
    // W^T tile: coalesced float4 loads, transposed scalar LDS stores
#pragma unroll
    for (int i = 0; i < 4; ++i) {
      int f = i * 256 + t;
      int e = f >> 4, j4 = f & 15;
      float4 v = *(const float4*)&W[(size_t)(e0 + e) * HS + j4 * 4];
      Bs[(j4 * 4 + 0) * 68 + e] = v.x;
      Bs[(j4 * 4 + 1) * 68 + e] = v.y;
      Bs[(j4 * 4 + 2) * 68 + e] = v.z;
      Bs[(j4 * 4 + 3) * 68 + e] = v.w;
    }
    __syncthreads();
#pragma unroll
    for (int d4 = 0; d4 < 16; ++d4) {
      float4 a[4], w[4];
#pragma unroll
      for (int ii = 0; ii < 4; ++ii)
        a[ii] = *(const float4*)&As[(ib + 16 * ii) * 68 + d4 * 4];
#pragma unroll
      for (int jj = 0; jj < 4; ++jj)
        w[jj] = *(const float4*)&Bs[(jb + 16 * jj) * 68 + d4 * 4];
#pragma unroll
      for (int ii = 0; ii < 4; ++ii)
#pragma unroll
        for (int jj = 0; jj < 4; ++jj)
          acc[ii][jj] += dot4f(a[ii], w[jj]);
    }
  }
#pragma unroll
  for (int ii = 0; ii < 4; ++ii)
#pragma unroll
    for (int jj = 0; jj < 4; ++jj)
      outp[(size_t)(tok0 + ib + 16 * ii) * HS + jb + 16 * jj] = acc[ii][jj];
}

// ---------------- Kernel 2: causal flash attention ----------------
// grid (T/64, NBATCH), block 256. 64-query tile per block, 64-key tiles.
// Thread (qb = t>>4, kb = t&15): S rows q = qb+16*qq, cols k = kb+16*kk.
// P overlays the K tile in LDS to stay under 64 KB static shared.
__global__ __launch_bounds__(256) void attn(
    const float* __restrict__ ws, float* __restrict__ out) {
  __shared__ float Qs[64 * 68];
  __shared__ float KPs[64 * 68];  // K tile, then P^T packed [k][qb*4+qq]
  __shared__ float Vs[64 * 68];
  const int t = threadIdx.x;
  const int qtile = blockIdx.x;
  const int b = blockIdx.y;
  const float* qp = ws;
  const float* kp = ws + (size_t)BT * HS;
  const float* vp = ws + 2 * (size_t)BT * HS;
  const int qb = t >> 4, kb = t & 15;
  const size_t qrow0 = (size_t)b * T_SEQ + (size_t)qtile * 64;

  // Q tile load (once)
#pragma unroll
  for (int i = 0; i < 4; ++i) {
    int f = i * 256 + t;
    int r = f >> 4, c4 = f & 15;
    *(float4*)&Qs[r * 68 + c4 * 4] =
        *(const float4*)&qp[(qrow0 + r) * HS + c4 * 4];
  }

  float m[4], l[4];
  float4 o4[4];
#pragma unroll
  for (int qq = 0; qq < 4; ++qq) {
    m[qq] = -1e30f; l[qq] = 0.f; o4[qq] = make_float4(0.f, 0.f, 0.f, 0.f);
  }

  for (int kt = 0; kt <= qtile; ++kt) {
    __syncthreads();  // prior iteration's readers of KPs/Vs done (and Q loaded)
    const size_t krow0 = (size_t)b * T_SEQ + (size_t)kt * 64;
#pragma unroll
    for (int i = 0; i < 4; ++i) {
      int f = i * 256 + t;
      int r = f >> 4, c4 = f & 15;
      *(float4*)&KPs[r * 68 + c4 * 4] =
          *(const float4*)&kp[(krow0 + r) * HS + c4 * 4];
      *(float4*)&Vs[r * 68 + c4 * 4] =
          *(const float4*)&vp[(krow0 + r) * HS + c4 * 4];
    }
    __syncthreads();

    // S = Q K^T (64-dim dot per element)
    float s[4][4] = {};
#pragma unroll
    for (int d4 = 0; d4 < 16; ++d4) {
      float4 a[4], kf[4];
#pragma unroll
      for (int qq = 0; qq < 4; ++qq)
        a[qq] = *(const float4*)&Qs[(qb + 16 * qq) * 68 + d4 * 4];
#pragma unroll
      for (int kk = 0; kk < 4; ++kk)
        kf[kk] = *(const float4*)&KPs[(kb + 16 * kk) * 68 + d4 * 4];
#pragma unroll
      for (int qq = 0; qq < 4; ++qq)
#pragma unroll
        for (int kk = 0; kk < 4; ++kk)
          s[qq][kk] += dot4f(a[qq], kf[kk]);
    }
    // causal mask on the diagonal tile
    if (kt == qtile) {
#pragma unroll
      for (int qq = 0; qq < 4; ++qq)
#pragma unroll
        for (int kk = 0; kk < 4; ++kk)
          if (kb + 16 * kk > qb + 16 * qq) s[qq][kk] = -1e30f;
    }
    // online softmax update (row groups = 16 lanes sharing qb; xor 1,2,4,8)
    float alpha[4];
#pragma unroll
    for (int qq = 0; qq < 4; ++qq) {
      float tm = fmaxf(fmaxf(s[qq][0], s[qq][1]), fmaxf(s[qq][2], s[qq][3]));
#pragma unroll
      for (int off = 1; off <= 8; off <<= 1)
        tm = fmaxf(tm, __shfl_xor(tm, off, 64));
      float mn = fmaxf(m[qq], tm);
      alpha[qq] = __expf(m[qq] - mn);
      float rs = 0.f;
#pragma unroll
      for (int kk = 0; kk < 4; ++kk) {
        s[qq][kk] = __expf(s[qq][kk] - mn);
        rs += s[qq][kk];
      }
#pragma unroll
      for (int off = 1; off <= 8; off <<= 1)
        rs += __shfl_xor(rs, off, 64);
      l[qq] = l[qq] * alpha[qq] + rs;
      m[qq] = mn;
    }
    __syncthreads();  // all waves done reading K from KPs
    // store P packed: KPs[k][qb*4+qq] so PV reads float4 over qq
#pragma unroll
    for (int qq = 0; qq < 4; ++qq)
#pragma unroll
      for (int kk = 0; kk < 4; ++kk)
        KPs[(kb + 16 * kk) * 68 + qb * 4 + qq] = s[qq][kk];
    __syncthreads();
    // O = alpha*O + P V
#pragma unroll
    for (int qq = 0; qq < 4; ++qq) {
      o4[qq].x *= alpha[qq]; o4[qq].y *= alpha[qq];
      o4[qq].z *= alpha[qq]; o4[qq].w *= alpha[qq];
    }
#pragma unroll 4
    for (int j = 0; j < 64; ++j) {
      float4 p4 = *(const float4*)&KPs[j * 68 + qb * 4];
      float4 v4 = *(const float4*)&Vs[j * 68 + kb * 4];
      o4[0].x += p4.x * v4.x; o4[0].y += p4.x * v4.y; o4[0].z += p4.x * v4.z; o4[0].w += p4.x * v4.w;
      o4[1].x += p4.y * v4.x; o4[1].y += p4.y * v4.y; o4[1].z += p4.y * v4.z; o4[1].w += p4.y * v4.w;
      o4[2].x += p4.z * v4.x; o4[2].y += p4.z * v4.y; o4[2].z += p4.z * v4.z; o4[2].w += p4.z * v4.w;
      o4[3].x += p4.w * v4.x; o4[3].y += p4.w * v4.y; o4[3].z += p4.w * v4.z; o4[3].w += p4.w * v4.w;
    }
  }
  // epilogue: out = O / (l * sqrt(HS));  sqrt(64) = 8 (ref divides AFTER softmax)
#pragma unroll
  for (int qq = 0; qq < 4; ++qq) {
    float inv = 1.f / (l[qq] * 8.0f);
    float4 r;
    r.x = o4[qq].x * inv; r.y = o4[qq].y * inv;
    r.z = o4[qq].z * inv; r.w = o4[qq].w * inv;
    *(float4*)&out[(qrow0 + qb + 16 * qq) * HS + kb * 4] = r;
  }
}

extern "C" void kernel_launch(void* const* d_in, const int* in_sizes, int n_in,
                              void* d_out, int out_size, void* d_ws, size_t ws_size,
                              hipStream_t stream) {
  const float* inp = (const float*)d_in[0];
  const float* Wq  = (const float*)d_in[1];
  const float* Wk  = (const float*)d_in[2];
  const float* Wv  = (const float*)d_in[3];
  float* out = (float*)d_out;
  float* ws  = (float*)d_ws;   // needs 3*BT*HS*4 = 12 MB for q,k,v

  dim3 g1(BT / 64, 3), blk(256);
  qkv_proj<<<g1, blk, 0, stream>>>(inp, Wq, Wk, Wv, ws);
  dim3 g2(T_SEQ / 64, NBATCH);
  attn<<<g2, blk, 0, stream>>>(ws, out);
}

// Round 3
// 455.918 us; speedup vs baseline: 2.0851x; 2.0851x over previous
//
#include <hip/hip_runtime.h>

#define T_SEQ 4096
#define NBATCH 4
#define EMB 1024
#define HS 64
#define BT (NBATCH * T_SEQ)   // 16384 token rows

typedef float f32x4 __attribute__((ext_vector_type(4)));
typedef short s16x8 __attribute__((ext_vector_type(8)));

__device__ __forceinline__ float dot4f(float4 a, float4 b) {
  return a.x * b.x + a.y * b.y + a.z * b.z + a.w * b.w;
}
__device__ __forceinline__ unsigned short f2bf(float x) {  // RNE fp32->bf16
  union { float f; unsigned u; } c; c.f = x;
  unsigned r = c.u + 0x7FFF + ((c.u >> 16) & 1);
  return (unsigned short)(r >> 16);
}
__device__ __forceinline__ float bf2f(unsigned short h) {
  union { unsigned u; float f; } c; c.u = ((unsigned)h) << 16;
  return c.f;
}

// ---------------- Kernel 1: QKV projection (fp32 core, mixed epilogue) ----
// grid (BT/64, 3), block 256. which: 0->q fp32, 1->k hi/lo bf16, 2->v^T bf16.
__global__ __launch_bounds__(256) void qkv_proj(
    const float* __restrict__ inp, const float* __restrict__ Wq,
    const float* __restrict__ Wk, const float* __restrict__ Wv,
    float* __restrict__ qf, unsigned short* __restrict__ khi,
    unsigned short* __restrict__ klo, unsigned short* __restrict__ vtb) {
  __shared__ float As[64 * 68];
  __shared__ float Bs[64 * 68];
  const int t = threadIdx.x;
  const int tile = blockIdx.x;
  const int which = blockIdx.y;
  const float* W = (which == 0) ? Wq : (which == 1) ? Wk : Wv;
  const int tok0 = tile * 64;
  const int ib = t >> 4, jb = t & 15;
  float acc[4][4] = {};

  for (int e0 = 0; e0 < EMB; e0 += 64) {
    __syncthreads();
#pragma unroll
    for (int i = 0; i < 4; ++i) {
      int f = i * 256 + t;
      int r = f >> 4, c4 = f & 15;
      float4 v = *(const float4*)&inp[(size_t)(tok0 + r) * EMB + e0 + c4 * 4];
      *(float4*)&As[r * 68 + c4 * 4] = v;
    }
#pragma unroll
    for (int i = 0; i < 4; ++i) {
      int f = i * 256 + t;
      int e = f >> 4, j4 = f & 15;
      float4 v = *(const float4*)&W[(size_t)(e0 + e) * HS + j4 * 4];
      Bs[(j4 * 4 + 0) * 68 + e] = v.x;
      Bs[(j4 * 4 + 1) * 68 + e] = v.y;
      Bs[(j4 * 4 + 2) * 68 + e] = v.z;
      Bs[(j4 * 4 + 3) * 68 + e] = v.w;
    }
    __syncthreads();
#pragma unroll
    for (int d4 = 0; d4 < 16; ++d4) {
      float4 a[4], w[4];
#pragma unroll
      for (int ii = 0; ii < 4; ++ii)
        a[ii] = *(const float4*)&As[(ib + 16 * ii) * 68 + d4 * 4];
#pragma unroll
      for (int jj = 0; jj < 4; ++jj)
        w[jj] = *(const float4*)&Bs[(jb + 16 * jj) * 68 + d4 * 4];
#pragma unroll
      for (int ii = 0; ii < 4; ++ii)
#pragma unroll
        for (int jj = 0; jj < 4; ++jj)
          acc[ii][jj] += dot4f(a[ii], w[jj]);
    }
  }

  if (which == 0) {
#pragma unroll
    for (int ii = 0; ii < 4; ++ii)
#pragma unroll
      for (int jj = 0; jj < 4; ++jj)
        qf[(size_t)(tok0 + ib + 16 * ii) * HS + jb + 16 * jj] = acc[ii][jj];
  } else if (which == 1) {
#pragma unroll
    for (int ii = 0; ii < 4; ++ii)
#pragma unroll
      for (int jj = 0; jj < 4; ++jj) {
        float x = acc[ii][jj];
        unsigned short h = f2bf(x);
        size_t idx = (size_t)(tok0 + ib + 16 * ii) * HS + jb + 16 * jj;
        khi[idx] = h;
        klo[idx] = f2bf(x - bf2f(h));
      }
  } else {
    // v transposed per 64-key tile: vtb[tile][h][key]
#pragma unroll
    for (int ii = 0; ii < 4; ++ii)
#pragma unroll
      for (int jj = 0; jj < 4; ++jj)
        vtb[(size_t)tile * 4096 + (size_t)(jb + 16 * jj) * 64 + (ib + 16 * ii)] =
            f2bf(acc[ii][jj]);
  }
}

// ---------------- Kernel 2: causal flash attention, bf16 MFMA ------------
// grid (T/64, NBATCH), block 256 = 4 waves. Wave w owns rows 16w..16w+15.
// QK^T: hi/lo bf16 split (3 mfma per K-chunk). PV: plain bf16.
// Layouts (m89/m120-verified): C/D: col=lane&15,row=quad*4+reg.
//   A-frag: [m=lane&15][k=quad*8+j]. B-frag: [n=lane&15][k=quad*8+j].
__global__ __launch_bounds__(256) void attn_mfma(
    const float* __restrict__ q, const unsigned short* __restrict__ khi,
    const unsigned short* __restrict__ klo, const unsigned short* __restrict__ vt,
    float* __restrict__ out) {
  __shared__ unsigned short Khi_s[64 * 72];  // [key][d], pad 72 -> 2-way banks
  __shared__ unsigned short Klo_s[64 * 72];
  __shared__ unsigned short Vt_s[64 * 72];   // [h][key]
  __shared__ unsigned short P_s[4 * 16 * 72];  // per-wave 16 rows [q][key]
  const int t = threadIdx.x;
  const int lane = t & 63, w = t >> 6;
  const int m = lane & 15, quad = lane >> 4;
  const int qtile = blockIdx.x, b = blockIdx.y;
  const size_t qrow0 = (size_t)b * T_SEQ + (size_t)qtile * 64;
  const size_t krowbase = (size_t)b * T_SEQ;

  // preload Q fragments hi/lo, chunks c (d = c*32 + quad*8 .. +8)
  s16x8 qh[2], ql[2];
#pragma unroll
  for (int c = 0; c < 2; ++c) {
    const float* qp = &q[(qrow0 + w * 16 + m) * HS + c * 32 + quad * 8];
    float4 x0 = *(const float4*)qp;
    float4 x1 = *(const float4*)(qp + 4);
    float xv[8] = {x0.x, x0.y, x0.z, x0.w, x1.x, x1.y, x1.z, x1.w};
#pragma unroll
    for (int j = 0; j < 8; ++j) {
      unsigned short h = f2bf(xv[j]);
      qh[c][j] = (short)h;
      ql[c][j] = (short)f2bf(xv[j] - bf2f(h));
    }
  }

  float mrow[4], lrow[4];
  f32x4 o[4];
#pragma unroll
  for (int r = 0; r < 4; ++r) { mrow[r] = -1e30f; lrow[r] = 0.f; }
#pragma unroll
  for (int hb = 0; hb < 4; ++hb) o[hb] = (f32x4){0.f, 0.f, 0.f, 0.f};

  for (int kt = 0; kt <= qtile; ++kt) {
    __syncthreads();  // prior iteration's LDS readers done
    // FULL tile staging: 64 rows x 64 bf16 = 512 uint4; 256 thr x 2 iters
#pragma unroll
    for (int i = 0; i < 2; ++i) {
      int f = i * 256 + t;          // 0..511
      int r = f >> 3, ch = f & 7;   // row, 8-short chunk
      size_t g = (krowbase + (size_t)kt * 64 + r) * HS + ch * 8;
      *(uint4*)&Khi_s[r * 72 + ch * 8] = *(const uint4*)&khi[g];
      *(uint4*)&Klo_s[r * 72 + ch * 8] = *(const uint4*)&klo[g];
      size_t gv = (size_t)(b * 64 + kt) * 4096 + (size_t)r * 64 + ch * 8;
      *(uint4*)&Vt_s[r * 72 + ch * 8] = *(const uint4*)&vt[gv];
    }
    __syncthreads();

    // S = Q K^T over 4 key col-blocks; hi*hi + hi*lo + lo*hi
    f32x4 s[4];
#pragma unroll
    for (int cb = 0; cb < 4; ++cb) {
      s[cb] = (f32x4){0.f, 0.f, 0.f, 0.f};
#pragma unroll
      for (int c = 0; c < 2; ++c) {
        s16x8 bh = *(const s16x8*)&Khi_s[(cb * 16 + m) * 72 + c * 32 + quad * 8];
        s16x8 bl = *(const s16x8*)&Klo_s[(cb * 16 + m) * 72 + c * 32 + quad * 8];
        s[cb] = __builtin_amdgcn_mfma_f32_16x16x32_bf16(qh[c], bh, s[cb], 0, 0, 0);
        s[cb] = __builtin_amdgcn_mfma_f32_16x16x32_bf16(qh[c], bl, s[cb], 0, 0, 0);
        s[cb] = __builtin_amdgcn_mfma_f32_16x16x32_bf16(ql[c], bh, s[cb], 0, 0, 0);
      }
    }
    if (kt == qtile) {  // causal mask on diagonal tile
#pragma unroll
      for (int cb = 0; cb < 4; ++cb)
#pragma unroll
        for (int r = 0; r < 4; ++r)
          if (cb * 16 + m > w * 16 + quad * 4 + r) s[cb][r] = -1e30f;
    }
    // online softmax per row r (row = quad*4+r, spread over 16 lanes)
    float alpha[4];
#pragma unroll
    for (int r = 0; r < 4; ++r) {
      float mx = fmaxf(fmaxf(s[0][r], s[1][r]), fmaxf(s[2][r], s[3][r]));
#pragma unroll
      for (int off = 1; off <= 8; off <<= 1) mx = fmaxf(mx, __shfl_xor(mx, off, 64));
      float mn = fmaxf(mrow[r], mx);
      alpha[r] = __expf(mrow[r] - mn);
      float rs = 0.f;
#pragma unroll
      for (int cb = 0; cb < 4; ++cb) {
        s[cb][r] = __expf(s[cb][r] - mn);
        rs += s[cb][r];
      }
#pragma unroll
      for (int off = 1; off <= 8; off <<= 1) rs += __shfl_xor(rs, off, 64);
      lrow[r] = lrow[r] * alpha[r] + rs;
      mrow[r] = mn;
#pragma unroll
      for (int hb = 0; hb < 4; ++hb) o[hb][r] *= alpha[r];
    }
    // P: C-layout -> LDS -> A-layout (wave-private region)
#pragma unroll
    for (int cb = 0; cb < 4; ++cb)
#pragma unroll
      for (int r = 0; r < 4; ++r)
        P_s[(w * 16 + quad * 4 + r) * 72 + cb * 16 + m] = f2bf(s[cb][r]);
    __syncthreads();  // forces lgkmcnt drain; uniform across block

    s16x8 pf[2];
#pragma unroll
    for (int c = 0; c < 2; ++c)
      pf[c] = *(const s16x8*)&P_s[(w * 16 + m) * 72 + c * 32 + quad * 8];
#pragma unroll
    for (int hb = 0; hb < 4; ++hb) {
#pragma unroll
      for (int c = 0; c < 2; ++c) {
        s16x8 vf = *(const s16x8*)&Vt_s[(hb * 16 + m) * 72 + c * 32 + quad * 8];
        o[hb] = __builtin_amdgcn_mfma_f32_16x16x32_bf16(pf[c], vf, o[hb], 0, 0, 0);
      }
    }
  }
  // epilogue: out = O / (l * 8)   (ref divides by sqrt(64) AFTER softmax)
#pragma unroll
  for (int r = 0; r < 4; ++r) {
    float inv = 1.f / (lrow[r] * 8.0f);
#pragma unroll
    for (int hb = 0; hb < 4; ++hb)
      out[(qrow0 + w * 16 + quad * 4 + r) * HS + hb * 16 + m] = o[hb][r] * inv;
  }
}

extern "C" void kernel_launch(void* const* d_in, const int* in_sizes, int n_in,
                              void* d_out, int out_size, void* d_ws, size_t ws_size,
                              hipStream_t stream) {
  const float* inp = (const float*)d_in[0];
  const float* Wq  = (const float*)d_in[1];
  const float* Wk  = (const float*)d_in[2];
  const float* Wv  = (const float*)d_in[3];
  float* out = (float*)d_out;

  // ws layout: q fp32 (4 MB) | khi bf16 (2 MB) | klo bf16 (2 MB) | vt bf16 (2 MB)
  float* qf = (float*)d_ws;
  unsigned short* khi = (unsigned short*)((char*)d_ws + (size_t)BT * HS * 4);
  unsigned short* klo = khi + (size_t)BT * HS;
  unsigned short* vtb = klo + (size_t)BT * HS;

  dim3 blk(256);
  qkv_proj<<<dim3(BT / 64, 3), blk, 0, stream>>>(inp, Wq, Wk, Wv, qf, khi, klo, vtb);
  attn_mfma<<<dim3(T_SEQ / 64, NBATCH), blk, 0, stream>>>(qf, khi, klo, vtb, out);
}

// Round 5
// 375.598 us; speedup vs baseline: 2.5309x; 1.2138x over previous
//
#include <hip/hip_runtime.h>

#define T_SEQ 4096
#define NBATCH 4
#define EMB 1024
#define HS 64
#define BT (NBATCH * T_SEQ)   // 16384 token rows

typedef float f32x4 __attribute__((ext_vector_type(4)));
typedef short s16x8 __attribute__((ext_vector_type(8)));

__device__ __forceinline__ unsigned short f2bf(float x) {  // RNE fp32->bf16
  union { float f; unsigned u; } c; c.f = x;
  unsigned r = c.u + 0x7FFF + ((c.u >> 16) & 1);
  return (unsigned short)(r >> 16);
}
__device__ __forceinline__ float bf2f(unsigned short h) {
  union { unsigned u; float f; } c; c.u = ((unsigned)h) << 16;
  return c.f;
}

// ---------------- Kernel 0: W -> W^T hi/lo bf16 (tiny, L2-resident) ------
// grid 192, block 256. wt[n3][k], n3 = which*64 + n.
__global__ __launch_bounds__(256) void wconv(
    const float* __restrict__ Wq, const float* __restrict__ Wk,
    const float* __restrict__ Wv, unsigned short* __restrict__ wt_hi,
    unsigned short* __restrict__ wt_lo) {
  const int n3 = blockIdx.x;
  const int which = n3 >> 6, n = n3 & 63;
  const float* W = (which == 0) ? Wq : (which == 1) ? Wk : Wv;
#pragma unroll
  for (int i = 0; i < 4; ++i) {
    int k = i * 256 + threadIdx.x;
    float x = W[(size_t)k * HS + n];
    unsigned short h = f2bf(x);
    wt_hi[(size_t)n3 * EMB + k] = h;
    wt_lo[(size_t)n3 * EMB + k] = f2bf(x - bf2f(h));
  }
}

// ---------------- Kernel 1: QKV projection, bf16 MFMA hi/lo --------------
// grid BT/64 = 256, block 512 = 8 waves. Wave w = (mg = w>>2, ng = w&3):
// rows mg*32 + mt*16 (mt<2), cols ng*48 + nt*16 (nt<3). BK=32 per iter.
// A: fp32 global -> registers -> hi/lo frags (no LDS). B: LDS, pad 40.
// Staging: 1536 uint4 = Bhi 768 (f<768, idx=f) + Blo 768 (idx=f-768).
// NOTE: f & 767 is WRONG here (767 lacks bit 8) — use explicit compare.
__global__ __launch_bounds__(512) void qkv_mfma(
    const float* __restrict__ inp, const unsigned short* __restrict__ wt_hi,
    const unsigned short* __restrict__ wt_lo, float* __restrict__ qf,
    unsigned short* __restrict__ khi, unsigned short* __restrict__ klo,
    unsigned short* __restrict__ vtb) {
  __shared__ unsigned short Bhi[192 * 40];  // stride 40 shorts: 2-way banks
  __shared__ unsigned short Blo[192 * 40];
  const int t = threadIdx.x, lane = t & 63, w = t >> 6;
  const int m = lane & 15, quad = lane >> 4;
  const int mg = w >> 2, ng = w & 3;
  const int tok0 = blockIdx.x * 64;

  f32x4 acc[2][3];
#pragma unroll
  for (int mt = 0; mt < 2; ++mt)
#pragma unroll
    for (int nt = 0; nt < 3; ++nt) acc[mt][nt] = (f32x4){0.f, 0.f, 0.f, 0.f};

  // register prefetch buffers
  uint4 bpre[3];
  float4 apre[2][2];

  // prefetch k-chunk 0
#pragma unroll
  for (int i = 0; i < 3; ++i) {
    int f = i * 512 + t;
    int idx = (f < 768) ? f : f - 768;
    const unsigned short* src = (f < 768) ? wt_hi : wt_lo;
    bpre[i] = *(const uint4*)&src[(size_t)(idx >> 2) * EMB + (idx & 3) * 8];
  }
#pragma unroll
  for (int mt = 0; mt < 2; ++mt) {
    const float* ap = &inp[(size_t)(tok0 + mg * 32 + mt * 16 + m) * EMB + quad * 8];
    apre[mt][0] = *(const float4*)ap;
    apre[mt][1] = *(const float4*)(ap + 4);
  }

  for (int kc = 0; kc < 32; ++kc) {
    const int k0n = (kc + 1) * 32;
    __syncthreads();  // previous iteration's B readers done
#pragma unroll
    for (int i = 0; i < 3; ++i) {
      int f = i * 512 + t;
      int idx = (f < 768) ? f : f - 768;
      unsigned short* dst = (f < 768) ? Bhi : Blo;
      *(uint4*)&dst[(idx >> 2) * 40 + (idx & 3) * 8] = bpre[i];
    }
    __syncthreads();

    // convert A prefetch regs -> hi/lo fragments
    s16x8 ah[2], al[2];
#pragma unroll
    for (int mt = 0; mt < 2; ++mt) {
      float xv[8] = {apre[mt][0].x, apre[mt][0].y, apre[mt][0].z, apre[mt][0].w,
                     apre[mt][1].x, apre[mt][1].y, apre[mt][1].z, apre[mt][1].w};
#pragma unroll
      for (int j = 0; j < 8; ++j) {
        unsigned short h = f2bf(xv[j]);
        ah[mt][j] = (short)h;
        al[mt][j] = (short)f2bf(xv[j] - bf2f(h));
      }
    }

    // issue next chunk's loads before compute (latency hiding)
    if (kc < 31) {
#pragma unroll
      for (int i = 0; i < 3; ++i) {
        int f = i * 512 + t;
        int idx = (f < 768) ? f : f - 768;
        const unsigned short* src = (f < 768) ? wt_hi : wt_lo;
        bpre[i] = *(const uint4*)&src[(size_t)(idx >> 2) * EMB + k0n + (idx & 3) * 8];
      }
#pragma unroll
      for (int mt = 0; mt < 2; ++mt) {
        const float* ap =
            &inp[(size_t)(tok0 + mg * 32 + mt * 16 + m) * EMB + k0n + quad * 8];
        apre[mt][0] = *(const float4*)ap;
        apre[mt][1] = *(const float4*)(ap + 4);
      }
    }

#pragma unroll
    for (int nt = 0; nt < 3; ++nt) {
      int n3 = ng * 48 + nt * 16 + m;
      s16x8 bh = *(const s16x8*)&Bhi[n3 * 40 + quad * 8];
      s16x8 bl = *(const s16x8*)&Blo[n3 * 40 + quad * 8];
#pragma unroll
      for (int mt = 0; mt < 2; ++mt) {
        acc[mt][nt] = __builtin_amdgcn_mfma_f32_16x16x32_bf16(ah[mt], bh, acc[mt][nt], 0, 0, 0);
        acc[mt][nt] = __builtin_amdgcn_mfma_f32_16x16x32_bf16(ah[mt], bl, acc[mt][nt], 0, 0, 0);
        acc[mt][nt] = __builtin_amdgcn_mfma_f32_16x16x32_bf16(al[mt], bh, acc[mt][nt], 0, 0, 0);
      }
    }
  }

  // epilogue: C row = quad*4+r (token), col = m (n3 = ng*48+nt*16+m)
#pragma unroll
  for (int mt = 0; mt < 2; ++mt)
#pragma unroll
    for (int nt = 0; nt < 3; ++nt) {
      int n3 = ng * 48 + nt * 16 + m;
      int which = n3 >> 6, col = n3 & 63;
#pragma unroll
      for (int r = 0; r < 4; ++r) {
        int tok = tok0 + mg * 32 + mt * 16 + quad * 4 + r;
        float val = acc[mt][nt][r];
        if (which == 0) {
          qf[(size_t)tok * HS + col] = val;
        } else if (which == 1) {
          unsigned short h = f2bf(val);
          khi[(size_t)tok * HS + col] = h;
          klo[(size_t)tok * HS + col] = f2bf(val - bf2f(h));
        } else {
          vtb[(size_t)blockIdx.x * 4096 + (size_t)col * 64 + (tok & 63)] = f2bf(val);
        }
      }
    }
}

// ---------------- Kernel 2: causal flash attention, bf16 MFMA ------------
// (unchanged from R3 — verified correct at absmax 1.95e-3)
__global__ __launch_bounds__(256) void attn_mfma(
    const float* __restrict__ q, const unsigned short* __restrict__ khi,
    const unsigned short* __restrict__ klo, const unsigned short* __restrict__ vt,
    float* __restrict__ out) {
  __shared__ unsigned short Khi_s[64 * 72];
  __shared__ unsigned short Klo_s[64 * 72];
  __shared__ unsigned short Vt_s[64 * 72];
  __shared__ unsigned short P_s[4 * 16 * 72];
  const int t = threadIdx.x;
  const int lane = t & 63, w = t >> 6;
  const int m = lane & 15, quad = lane >> 4;
  const int qtile = blockIdx.x, b = blockIdx.y;
  const size_t qrow0 = (size_t)b * T_SEQ + (size_t)qtile * 64;
  const size_t krowbase = (size_t)b * T_SEQ;

  s16x8 qh[2], ql[2];
#pragma unroll
  for (int c = 0; c < 2; ++c) {
    const float* qp = &q[(qrow0 + w * 16 + m) * HS + c * 32 + quad * 8];
    float4 x0 = *(const float4*)qp;
    float4 x1 = *(const float4*)(qp + 4);
    float xv[8] = {x0.x, x0.y, x0.z, x0.w, x1.x, x1.y, x1.z, x1.w};
#pragma unroll
    for (int j = 0; j < 8; ++j) {
      unsigned short h = f2bf(xv[j]);
      qh[c][j] = (short)h;
      ql[c][j] = (short)f2bf(xv[j] - bf2f(h));
    }
  }

  float mrow[4], lrow[4];
  f32x4 o[4];
#pragma unroll
  for (int r = 0; r < 4; ++r) { mrow[r] = -1e30f; lrow[r] = 0.f; }
#pragma unroll
  for (int hb = 0; hb < 4; ++hb) o[hb] = (f32x4){0.f, 0.f, 0.f, 0.f};

  for (int kt = 0; kt <= qtile; ++kt) {
    __syncthreads();
#pragma unroll
    for (int i = 0; i < 2; ++i) {
      int f = i * 256 + t;
      int r = f >> 3, ch = f & 7;
      size_t g = (krowbase + (size_t)kt * 64 + r) * HS + ch * 8;
      *(uint4*)&Khi_s[r * 72 + ch * 8] = *(const uint4*)&khi[g];
      *(uint4*)&Klo_s[r * 72 + ch * 8] = *(const uint4*)&klo[g];
      size_t gv = (size_t)(b * 64 + kt) * 4096 + (size_t)r * 64 + ch * 8;
      *(uint4*)&Vt_s[r * 72 + ch * 8] = *(const uint4*)&vt[gv];
    }
    __syncthreads();

    f32x4 s[4];
#pragma unroll
    for (int cb = 0; cb < 4; ++cb) {
      s[cb] = (f32x4){0.f, 0.f, 0.f, 0.f};
#pragma unroll
      for (int c = 0; c < 2; ++c) {
        s16x8 bh = *(const s16x8*)&Khi_s[(cb * 16 + m) * 72 + c * 32 + quad * 8];
        s16x8 bl = *(const s16x8*)&Klo_s[(cb * 16 + m) * 72 + c * 32 + quad * 8];
        s[cb] = __builtin_amdgcn_mfma_f32_16x16x32_bf16(qh[c], bh, s[cb], 0, 0, 0);
        s[cb] = __builtin_amdgcn_mfma_f32_16x16x32_bf16(qh[c], bl, s[cb], 0, 0, 0);
        s[cb] = __builtin_amdgcn_mfma_f32_16x16x32_bf16(ql[c], bh, s[cb], 0, 0, 0);
      }
    }
    if (kt == qtile) {
#pragma unroll
      for (int cb = 0; cb < 4; ++cb)
#pragma unroll
        for (int r = 0; r < 4; ++r)
          if (cb * 16 + m > w * 16 + quad * 4 + r) s[cb][r] = -1e30f;
    }
    float alpha[4];
#pragma unroll
    for (int r = 0; r < 4; ++r) {
      float mx = fmaxf(fmaxf(s[0][r], s[1][r]), fmaxf(s[2][r], s[3][r]));
#pragma unroll
      for (int off = 1; off <= 8; off <<= 1) mx = fmaxf(mx, __shfl_xor(mx, off, 64));
      float mn = fmaxf(mrow[r], mx);
      alpha[r] = __expf(mrow[r] - mn);
      float rs = 0.f;
#pragma unroll
      for (int cb = 0; cb < 4; ++cb) {
        s[cb][r] = __expf(s[cb][r] - mn);
        rs += s[cb][r];
      }
#pragma unroll
      for (int off = 1; off <= 8; off <<= 1) rs += __shfl_xor(rs, off, 64);
      lrow[r] = lrow[r] * alpha[r] + rs;
      mrow[r] = mn;
#pragma unroll
      for (int hb = 0; hb < 4; ++hb) o[hb][r] *= alpha[r];
    }
#pragma unroll
    for (int cb = 0; cb < 4; ++cb)
#pragma unroll
      for (int r = 0; r < 4; ++r)
        P_s[(w * 16 + quad * 4 + r) * 72 + cb * 16 + m] = f2bf(s[cb][r]);
    __syncthreads();

    s16x8 pf[2];
#pragma unroll
    for (int c = 0; c < 2; ++c)
      pf[c] = *(const s16x8*)&P_s[(w * 16 + m) * 72 + c * 32 + quad * 8];
#pragma unroll
    for (int hb = 0; hb < 4; ++hb) {
#pragma unroll
      for (int c = 0; c < 2; ++c) {
        s16x8 vf = *(const s16x8*)&Vt_s[(hb * 16 + m) * 72 + c * 32 + quad * 8];
        o[hb] = __builtin_amdgcn_mfma_f32_16x16x32_bf16(pf[c], vf, o[hb], 0, 0, 0);
      }
    }
  }
#pragma unroll
  for (int r = 0; r < 4; ++r) {
    float inv = 1.f / (lrow[r] * 8.0f);
#pragma unroll
    for (int hb = 0; hb < 4; ++hb)
      out[(qrow0 + w * 16 + quad * 4 + r) * HS + hb * 16 + m] = o[hb][r] * inv;
  }
}

extern "C" void kernel_launch(void* const* d_in, const int* in_sizes, int n_in,
                              void* d_out, int out_size, void* d_ws, size_t ws_size,
                              hipStream_t stream) {
  const float* inp = (const float*)d_in[0];
  const float* Wq  = (const float*)d_in[1];
  const float* Wk  = (const float*)d_in[2];
  const float* Wv  = (const float*)d_in[3];
  float* out = (float*)d_out;

  // ws: q f32 4MB | khi 2MB | klo 2MB | vt 2MB | wt_hi 384KB | wt_lo 384KB
  float* qf = (float*)d_ws;
  unsigned short* khi = (unsigned short*)((char*)d_ws + (size_t)BT * HS * 4);
  unsigned short* klo = khi + (size_t)BT * HS;
  unsigned short* vtb = klo + (size_t)BT * HS;
  unsigned short* wt_hi = vtb + (size_t)BT * HS;
  unsigned short* wt_lo = wt_hi + (size_t)192 * EMB;

  wconv<<<dim3(192), dim3(256), 0, stream>>>(Wq, Wk, Wv, wt_hi, wt_lo);
  qkv_mfma<<<dim3(BT / 64), dim3(512), 0, stream>>>(inp, wt_hi, wt_lo, qf, khi, klo, vtb);
  attn_mfma<<<dim3(T_SEQ / 64, NBATCH), dim3(256), 0, stream>>>(qf, khi, klo, vtb, out);
}

// Round 6
// 209.739 us; speedup vs baseline: 4.5324x; 1.7908x over previous
//
#include <hip/hip_runtime.h>

#define T_SEQ 4096
#define NBATCH 4
#define EMB 1024
#define HS 64
#define BT (NBATCH * T_SEQ)   // 16384 token rows

typedef float f32x4 __attribute__((ext_vector_type(4)));
typedef short s16x8 __attribute__((ext_vector_type(8)));

__device__ __forceinline__ unsigned short f2bf(float x) {  // RNE fp32->bf16
  union { float f; unsigned u; } c; c.f = x;
  unsigned r = c.u + 0x7FFF + ((c.u >> 16) & 1);
  return (unsigned short)(r >> 16);
}
__device__ __forceinline__ float bf2f(unsigned short h) {
  union { unsigned u; float f; } c; c.u = ((unsigned)h) << 16;
  return c.f;
}

// ---------------- Kernel 0: W -> W^T hi/lo bf16 (tiny, L2-resident) ------
__global__ __launch_bounds__(256) void wconv(
    const float* __restrict__ Wq, const float* __restrict__ Wk,
    const float* __restrict__ Wv, unsigned short* __restrict__ wt_hi,
    unsigned short* __restrict__ wt_lo) {
  const int n3 = blockIdx.x;
  const int which = n3 >> 6, n = n3 & 63;
  const float* W = (which == 0) ? Wq : (which == 1) ? Wk : Wv;
#pragma unroll
  for (int i = 0; i < 4; ++i) {
    int k = i * 256 + threadIdx.x;
    float x = W[(size_t)k * HS + n];
    unsigned short h = f2bf(x);
    wt_hi[(size_t)n3 * EMB + k] = h;
    wt_lo[(size_t)n3 * EMB + k] = f2bf(x - bf2f(h));
  }
}

// ---------------- Kernel 1: QKV projection, bf16 MFMA hi/lo --------------
// grid 256, block 1024 = 16 waves (4/SIMD). Wave w: mg = w>>2 (16-row group),
// ng = w&3 (48-col group, 3 nt). BK=32/iter. A: regs->hi/lo. B: LDS pad 40.
// B staging coverage (1536 uint4): t<768 -> Bhi[t]; t>=768 -> Blo[t-768];
// second pass t<512 -> Blo[256+t]. Full, disjoint. (R2/R4 lesson: verify!)
__global__ __launch_bounds__(1024) void qkv_mfma(
    const float* __restrict__ inp, const unsigned short* __restrict__ wt_hi,
    const unsigned short* __restrict__ wt_lo, float* __restrict__ qf,
    unsigned short* __restrict__ khi, unsigned short* __restrict__ klo,
    unsigned short* __restrict__ vtb) {
  __shared__ unsigned short Bhi[192 * 40];
  __shared__ unsigned short Blo[192 * 40];
  const int t = threadIdx.x, lane = t & 63, w = t >> 6;
  const int m = lane & 15, quad = lane >> 4;
  const int mg = w >> 2, ng = w & 3;
  const int tok0 = blockIdx.x * 64;
  const int arow = tok0 + mg * 16 + m;

  f32x4 acc[3];
#pragma unroll
  for (int nt = 0; nt < 3; ++nt) acc[nt] = (f32x4){0.f, 0.f, 0.f, 0.f};

  uint4 bpre0, bpre1;
  float4 apre0, apre1;

  const int idx0 = (t < 768) ? t : t - 768;
  const unsigned short* bsrc0 = (t < 768) ? wt_hi : wt_lo;
  // prefetch k-chunk 0
  bpre0 = *(const uint4*)&bsrc0[(size_t)(idx0 >> 2) * EMB + (idx0 & 3) * 8];
  if (t < 512)
    bpre1 = *(const uint4*)&wt_lo[(size_t)((256 + t) >> 2) * EMB + ((256 + t) & 3) * 8];
  {
    const float* ap = &inp[(size_t)arow * EMB + quad * 8];
    apre0 = *(const float4*)ap;
    apre1 = *(const float4*)(ap + 4);
  }

  for (int kc = 0; kc < 32; ++kc) {
    const int k0n = (kc + 1) * 32;
    __syncthreads();  // previous iteration's B readers done
    {
      unsigned short* dst0 = (t < 768) ? Bhi : Blo;
      *(uint4*)&dst0[(idx0 >> 2) * 40 + (idx0 & 3) * 8] = bpre0;
      if (t < 512)
        *(uint4*)&Blo[((256 + t) >> 2) * 40 + ((256 + t) & 3) * 8] = bpre1;
    }
    __syncthreads();

    // convert A prefetch regs -> hi/lo fragments
    s16x8 ah, al;
    {
      float xv[8] = {apre0.x, apre0.y, apre0.z, apre0.w,
                     apre1.x, apre1.y, apre1.z, apre1.w};
#pragma unroll
      for (int j = 0; j < 8; ++j) {
        unsigned short h = f2bf(xv[j]);
        ah[j] = (short)h;
        al[j] = (short)f2bf(xv[j] - bf2f(h));
      }
    }

    if (kc < 31) {  // issue next chunk's loads early
      bpre0 = *(const uint4*)&bsrc0[(size_t)(idx0 >> 2) * EMB + k0n + (idx0 & 3) * 8];
      if (t < 512)
        bpre1 = *(const uint4*)&wt_lo[(size_t)((256 + t) >> 2) * EMB + k0n + ((256 + t) & 3) * 8];
      const float* ap = &inp[(size_t)arow * EMB + k0n + quad * 8];
      apre0 = *(const float4*)ap;
      apre1 = *(const float4*)(ap + 4);
    }

#pragma unroll
    for (int nt = 0; nt < 3; ++nt) {
      int n3 = ng * 48 + nt * 16 + m;
      s16x8 bh = *(const s16x8*)&Bhi[n3 * 40 + quad * 8];
      s16x8 bl = *(const s16x8*)&Blo[n3 * 40 + quad * 8];
      acc[nt] = __builtin_amdgcn_mfma_f32_16x16x32_bf16(ah, bh, acc[nt], 0, 0, 0);
      acc[nt] = __builtin_amdgcn_mfma_f32_16x16x32_bf16(ah, bl, acc[nt], 0, 0, 0);
      acc[nt] = __builtin_amdgcn_mfma_f32_16x16x32_bf16(al, bh, acc[nt], 0, 0, 0);
    }
  }

  // epilogue: C row = quad*4+r (token), col = m
#pragma unroll
  for (int nt = 0; nt < 3; ++nt) {
    int n3 = ng * 48 + nt * 16 + m;
    int which = n3 >> 6, col = n3 & 63;
#pragma unroll
    for (int r = 0; r < 4; ++r) {
      int tok = tok0 + mg * 16 + quad * 4 + r;
      float val = acc[nt][r];
      if (which == 0) {
        qf[(size_t)tok * HS + col] = val;
      } else if (which == 1) {
        unsigned short h = f2bf(val);
        khi[(size_t)tok * HS + col] = h;
        klo[(size_t)tok * HS + col] = f2bf(val - bf2f(h));
      } else {
        vtb[(size_t)blockIdx.x * 4096 + (size_t)col * 64 + (tok & 63)] = f2bf(val);
      }
    }
  }
}

// ---------------- Kernel 2a: flash attention partials (split-K) ----------
// Work unit = (b, qtile, chunk of 16 k-tiles). Per batch: sum (qtile>>4)+1
// = 160 units; grid 640, block 256 = 4 waves. Writes un-normalized partial
// O (fp32, C-layout rows) + per-row m,l to slot (b*64+qtile)*4 + chunk.
__global__ __launch_bounds__(256) void attn_part(
    const float* __restrict__ q, const unsigned short* __restrict__ khi,
    const unsigned short* __restrict__ klo, const unsigned short* __restrict__ vt,
    float* __restrict__ partO, float* __restrict__ partML) {
  __shared__ unsigned short Khi_s[64 * 72];
  __shared__ unsigned short Klo_s[64 * 72];
  __shared__ unsigned short Vt_s[64 * 72];
  __shared__ unsigned short P_s[4 * 16 * 72];
  const int t = threadIdx.x;
  const int lane = t & 63, w = t >> 6;
  const int m = lane & 15, quad = lane >> 4;

  // map blockIdx.x -> (b, qtile, chunk)
  int u = blockIdx.x;
  const int b = u / 160;
  u -= b * 160;
  int qtile = 0, c = 0;
  {
    int acc = 0;
    for (int qq = 0; qq < 64; ++qq) {
      int ncq = (qq >> 4) + 1;
      if (u < acc + ncq) { qtile = qq; c = u - acc; break; }
      acc += ncq;
    }
  }
  const int kt0 = c * 16;
  const int kt1 = (kt0 + 16 < qtile + 1) ? kt0 + 16 : qtile + 1;

  const size_t qrow0 = (size_t)b * T_SEQ + (size_t)qtile * 64;
  const size_t krowbase = (size_t)b * T_SEQ;

  // Q fragments hi/lo
  s16x8 qh[2], ql[2];
#pragma unroll
  for (int cc = 0; cc < 2; ++cc) {
    const float* qp = &q[(qrow0 + w * 16 + m) * HS + cc * 32 + quad * 8];
    float4 x0 = *(const float4*)qp;
    float4 x1 = *(const float4*)(qp + 4);
    float xv[8] = {x0.x, x0.y, x0.z, x0.w, x1.x, x1.y, x1.z, x1.w};
#pragma unroll
    for (int j = 0; j < 8; ++j) {
      unsigned short h = f2bf(xv[j]);
      qh[cc][j] = (short)h;
      ql[cc][j] = (short)f2bf(xv[j] - bf2f(h));
    }
  }

  float mrow[4], lrow[4];
  f32x4 o[4];
#pragma unroll
  for (int r = 0; r < 4; ++r) { mrow[r] = -1e30f; lrow[r] = 0.f; }
#pragma unroll
  for (int hb = 0; hb < 4; ++hb) o[hb] = (f32x4){0.f, 0.f, 0.f, 0.f};

  for (int kt = kt0; kt < kt1; ++kt) {
    __syncthreads();
    // full-coverage staging: 512 uint4 per buffer, 256 thr x 2 iters
#pragma unroll
    for (int i = 0; i < 2; ++i) {
      int f = i * 256 + t;
      int r = f >> 3, ch = f & 7;
      size_t g = (krowbase + (size_t)kt * 64 + r) * HS + ch * 8;
      *(uint4*)&Khi_s[r * 72 + ch * 8] = *(const uint4*)&khi[g];
      *(uint4*)&Klo_s[r * 72 + ch * 8] = *(const uint4*)&klo[g];
      size_t gv = (size_t)(b * 64 + kt) * 4096 + (size_t)r * 64 + ch * 8;
      *(uint4*)&Vt_s[r * 72 + ch * 8] = *(const uint4*)&vt[gv];
    }
    __syncthreads();

    f32x4 s[4];
#pragma unroll
    for (int cb = 0; cb < 4; ++cb) {
      s[cb] = (f32x4){0.f, 0.f, 0.f, 0.f};
#pragma unroll
      for (int cc = 0; cc < 2; ++cc) {
        s16x8 bh = *(const s16x8*)&Khi_s[(cb * 16 + m) * 72 + cc * 32 + quad * 8];
        s16x8 bl = *(const s16x8*)&Klo_s[(cb * 16 + m) * 72 + cc * 32 + quad * 8];
        s[cb] = __builtin_amdgcn_mfma_f32_16x16x32_bf16(qh[cc], bh, s[cb], 0, 0, 0);
        s[cb] = __builtin_amdgcn_mfma_f32_16x16x32_bf16(qh[cc], bl, s[cb], 0, 0, 0);
        s[cb] = __builtin_amdgcn_mfma_f32_16x16x32_bf16(ql[cc], bh, s[cb], 0, 0, 0);
      }
    }
    if (kt == qtile) {  // causal mask on diagonal tile
#pragma unroll
      for (int cb = 0; cb < 4; ++cb)
#pragma unroll
        for (int r = 0; r < 4; ++r)
          if (cb * 16 + m > w * 16 + quad * 4 + r) s[cb][r] = -1e30f;
    }
    float alpha[4];
#pragma unroll
    for (int r = 0; r < 4; ++r) {
      float mx = fmaxf(fmaxf(s[0][r], s[1][r]), fmaxf(s[2][r], s[3][r]));
#pragma unroll
      for (int off = 1; off <= 8; off <<= 1) mx = fmaxf(mx, __shfl_xor(mx, off, 64));
      float mn = fmaxf(mrow[r], mx);
      alpha[r] = __expf(mrow[r] - mn);
      float rs = 0.f;
#pragma unroll
      for (int cb = 0; cb < 4; ++cb) {
        s[cb][r] = __expf(s[cb][r] - mn);
        rs += s[cb][r];
      }
#pragma unroll
      for (int off = 1; off <= 8; off <<= 1) rs += __shfl_xor(rs, off, 64);
      lrow[r] = lrow[r] * alpha[r] + rs;
      mrow[r] = mn;
#pragma unroll
      for (int hb = 0; hb < 4; ++hb) o[hb][r] *= alpha[r];
    }
#pragma unroll
    for (int cb = 0; cb < 4; ++cb)
#pragma unroll
      for (int r = 0; r < 4; ++r)
        P_s[(w * 16 + quad * 4 + r) * 72 + cb * 16 + m] = f2bf(s[cb][r]);
    __syncthreads();

    s16x8 pf[2];
#pragma unroll
    for (int cc = 0; cc < 2; ++cc)
      pf[cc] = *(const s16x8*)&P_s[(w * 16 + m) * 72 + cc * 32 + quad * 8];
#pragma unroll
    for (int hb = 0; hb < 4; ++hb) {
#pragma unroll
      for (int cc = 0; cc < 2; ++cc) {
        s16x8 vf = *(const s16x8*)&Vt_s[(hb * 16 + m) * 72 + cc * 32 + quad * 8];
        o[hb] = __builtin_amdgcn_mfma_f32_16x16x32_bf16(pf[cc], vf, o[hb], 0, 0, 0);
      }
    }
  }

  // write partial: un-normalized O + per-row m,l
  const int slot = ((b * 64 + qtile) << 2) + c;
  float* Op = partO + (size_t)slot * 4096;
#pragma unroll
  for (int r = 0; r < 4; ++r) {
    int row = w * 16 + quad * 4 + r;
#pragma unroll
    for (int hb = 0; hb < 4; ++hb) Op[row * 64 + hb * 16 + m] = o[hb][r];
    if (m == 0) {
      partML[(size_t)slot * 128 + row] = mrow[r];
      partML[(size_t)slot * 128 + 64 + row] = lrow[r];
    }
  }
}

// ---------------- Kernel 2b: combine partials -----------------------------
// grid (64, NBATCH), block 256: thread (row = t>>2, hg = t&3) -> 16 cols.
__global__ __launch_bounds__(256) void attn_combine(
    const float* __restrict__ partO, const float* __restrict__ partML,
    float* __restrict__ out) {
  const int qtile = blockIdx.x, b = blockIdx.y;
  const int t = threadIdx.x;
  const int row = t >> 2, hg = t & 3;
  const int nc = (qtile >> 4) + 1;
  const int slot0 = (b * 64 + qtile) << 2;

  float mv[4], lv[4], wgt[4];
  float mg = -1e30f;
  for (int i = 0; i < nc; ++i) {
    mv[i] = partML[(size_t)(slot0 + i) * 128 + row];
    lv[i] = partML[(size_t)(slot0 + i) * 128 + 64 + row];
    mg = fmaxf(mg, mv[i]);
  }
  float lsum = 0.f;
  for (int i = 0; i < nc; ++i) {
    wgt[i] = __expf(mv[i] - mg);
    lsum += wgt[i] * lv[i];
  }
  const float inv = 1.f / (lsum * 8.0f);  // ref divides by sqrt(64) after softmax

  float4 acc[4] = {make_float4(0.f, 0.f, 0.f, 0.f), make_float4(0.f, 0.f, 0.f, 0.f),
                   make_float4(0.f, 0.f, 0.f, 0.f), make_float4(0.f, 0.f, 0.f, 0.f)};
  for (int i = 0; i < nc; ++i) {
    const float* Op = partO + (size_t)(slot0 + i) * 4096 + row * 64 + hg * 16;
    float wg = wgt[i];
#pragma unroll
    for (int v = 0; v < 4; ++v) {
      float4 x = ((const float4*)Op)[v];
      acc[v].x += wg * x.x; acc[v].y += wg * x.y;
      acc[v].z += wg * x.z; acc[v].w += wg * x.w;
    }
  }
  float* op = &out[((size_t)b * T_SEQ + (size_t)qtile * 64 + row) * HS + hg * 16];
#pragma unroll
  for (int v = 0; v < 4; ++v) {
    float4 r;
    r.x = acc[v].x * inv; r.y = acc[v].y * inv;
    r.z = acc[v].z * inv; r.w = acc[v].w * inv;
    ((float4*)op)[v] = r;
  }
}

extern "C" void kernel_launch(void* const* d_in, const int* in_sizes, int n_in,
                              void* d_out, int out_size, void* d_ws, size_t ws_size,
                              hipStream_t stream) {
  const float* inp = (const float*)d_in[0];
  const float* Wq  = (const float*)d_in[1];
  const float* Wk  = (const float*)d_in[2];
  const float* Wv  = (const float*)d_in[3];
  float* out = (float*)d_out;

  // ws: qf 4MB | khi 2MB | klo 2MB | vt 2MB | wt_hi .375MB | wt_lo .375MB
  //     | partO 16MB | partML .5MB   (~27.3 MB total)
  char* base = (char*)d_ws;
  float* qf = (float*)base;
  unsigned short* khi = (unsigned short*)(base + (size_t)BT * HS * 4);
  unsigned short* klo = khi + (size_t)BT * HS;
  unsigned short* vtb = klo + (size_t)BT * HS;
  unsigned short* wt_hi = vtb + (size_t)BT * HS;
  unsigned short* wt_lo = wt_hi + (size_t)192 * EMB;
  float* partO = (float*)(wt_lo + (size_t)192 * EMB);
  float* partML = partO + (size_t)1024 * 4096;

  wconv<<<dim3(192), dim3(256), 0, stream>>>(Wq, Wk, Wv, wt_hi, wt_lo);
  qkv_mfma<<<dim3(BT / 64), dim3(1024), 0, stream>>>(inp, wt_hi, wt_lo, qf, khi, klo, vtb);
  attn_part<<<dim3(640), dim3(256), 0, stream>>>(qf, khi, klo, vtb, partO, partML);
  attn_combine<<<dim3(64, NBATCH), dim3(256), 0, stream>>>(partO, partML, out);
}